// Round 8
// baseline (356.620 us; speedup 1.0000x reference)
//
#include <hip/hip_runtime.h>
#include <math.h>

#define BATCH 128
#define S 50
#define D 128
#define SAMPLE 12

typedef __attribute__((ext_vector_type(8))) short short8v;
typedef __attribute__((ext_vector_type(4))) float f32x4;
typedef unsigned short u16;

__device__ __forceinline__ float leakyf(float x) { return x >= 0.f ? x : 0.2f * x; }
__device__ __forceinline__ u16 f2bf(float f) {
    union { float f; unsigned u; } v; v.f = f;
    unsigned u = v.u;
    return (u16)((u + 0x7FFFu + ((u >> 16) & 1u)) >> 16);  // RNE
}
__device__ __forceinline__ float bf2f(u16 h) {
    union { float f; unsigned u; } v; v.u = ((unsigned)h) << 16; return v.f;
}

// ---------------------------------------------------------------------------
// setup1: session + n1 (1-hop indices) + nw0 (1-hop weights)
// ---------------------------------------------------------------------------
__global__ __launch_bounds__(256) void setup1_kernel(
    const int* __restrict__ item, const int* __restrict__ mask,
    const int* __restrict__ inputs, const int* __restrict__ adj_all,
    const float* __restrict__ num_weight, const float* __restrict__ emb,
    float* __restrict__ session, int* __restrict__ n1, float* __restrict__ nw0)
{
    const int bx = blockIdx.x, t = threadIdx.x;
    if (bx < BATCH) {
        if (t < 128) {
            float num = 0.f, den = 0.f;
            for (int s = 0; s < S; ++s) {
                float m = (float)mask[bx * S + s];
                num += m * emb[item[bx * S + s] * D + t];
                den += m;
            }
            session[bx * D + t] = num / den;
        }
    } else {
        int idx = (bx - BATCH) * 256 + t;
        if (idx < BATCH * 600) {
            int b = idx / 600, j = idx % 600;
            int node = inputs[b * S + j / SAMPLE];
            n1[idx]  = adj_all[node * SAMPLE + j % SAMPLE];
            nw0[idx] = num_weight[node * SAMPLE + j % SAMPLE];
        }
    }
}

// ---------------------------------------------------------------------------
// prep2: emb->bf16, sessW1 bf16, W3T bf16, and PERMUTED gather tables:
//   n2p[b][lblk][i][c] / n1p[...]: byte offsets into emb_bf in staging order
//   nw1[b][7200]: 2-hop weights in true sample order
// ---------------------------------------------------------------------------
__global__ __launch_bounds__(256) void prep2_kernel(
    const float* __restrict__ emb, const float* __restrict__ w1,
    const float* __restrict__ w3, const float* __restrict__ session,
    const int* __restrict__ adj_all, const float* __restrict__ num_weight,
    const int* __restrict__ n1,
    u16* __restrict__ emb_bf, u16* __restrict__ sw1, u16* __restrict__ w3t,
    int* __restrict__ n2p, int* __restrict__ n1p, float* __restrict__ nw1)
{
    const int bx = blockIdx.x, t = threadIdx.x;
    if (bx < 2500) {                       // embedding -> bf16, 8 elems/thread
        int idx = bx * 256 + t;
        const float4* src = reinterpret_cast<const float4*>(emb) + (size_t)idx * 2;
        float4 a = src[0], c = src[1];
        u16 o[8] = {f2bf(a.x), f2bf(a.y), f2bf(a.z), f2bf(a.w),
                    f2bf(c.x), f2bf(c.y), f2bf(c.z), f2bf(c.w)};
        *reinterpret_cast<uint4*>(emb_bf + (size_t)idx * 8) = *reinterpret_cast<uint4*>(o);
    } else if (bx < 2756) {                // sessW1: block = (hop,b)
        int id = bx - 2500, hop = id >> 7, b = id & 127;
        const float* w1s = w1 + hop * 129 * 128;
        const float* se = session + b * 128;
        int n = t >> 1, kh = (t & 1) * 64;
        u16* dst = sw1 + (((size_t)(hop * 128 + b) * 128 + n) * 128) + kh;
        for (int kq = 0; kq < 64; kq += 8) {
            u16 o[8];
            #pragma unroll
            for (int e = 0; e < 8; ++e) { int k = kh + kq + e; o[e] = f2bf(w1s[k * 128 + n] * se[k]); }
            *reinterpret_cast<uint4*>(dst + kq) = *reinterpret_cast<uint4*>(o);
        }
    } else if (bx < 2788) {                // W3T [hop][n][k]
        int j = (bx - 2756) * 256 + t;     // < 8192
        int hop = j >> 12, r = j & 4095, n = r >> 5, k0 = (r & 31) * 8;
        const float* w3s = w3 + hop * 256 * 128;
        u16 o[8];
        #pragma unroll
        for (int e = 0; e < 8; ++e) o[e] = f2bf(w3s[(k0 + e) * 128 + n]);
        *reinterpret_cast<uint4*>(w3t + ((size_t)hop * 128 + n) * 256 + k0) = *reinterpret_cast<uint4*>(o);
    } else if (bx < 6388) {                // n2p (permuted byte-offsets) + nw1
        int idx = (bx - 2788) * 256 + t;
        if (idx < BATCH * 7200) {
            int b = idx / 7200, r = idx % 7200;
            int lblk = r / 96, q = r % 96;
            int i = q >> 4, c = q & 15;
            int gm = lblk * 96 + (c >> 2) * 24 + i * 4 + (c & 3);
            int node = n1[b * 600 + gm / SAMPLE];
            int s = gm % SAMPLE;
            n2p[idx] = adj_all[node * SAMPLE + s] << 8;
            nw1[b * 7200 + gm] = num_weight[node * SAMPLE + s];
        }
    } else {                               // n1p (mode0, permuted byte-offsets)
        int idx = (bx - 6388) * 256 + t;
        if (idx < BATCH * 672) {
            int b = idx / 672, r = idx % 672;
            int lblk = r / 96, q = r % 96;
            int i = q >> 4, c = q & 15;
            int gm = lblk * 96 + (c >> 2) * 24 + i * 4 + (c & 3);
            int jc = (gm < 600) ? gm : 0;
            n1p[idx] = n1[b * 600 + jc] << 8;
        }
    }
}

// fragment-slot XOR swizzle: spreads phase-4 scalar reads over all 32 banks
// while keeping GEMM1's ds_read_b128 a within-group lane permutation (free).
__device__ __forceinline__ int swz(int cg, int kk) { return ((kk & 1) << 2) | cg; }

// ---------------------------------------------------------------------------
// Fused main kernel. 8 l-rows (96 samples) per block, 4 waves, 3 barriers.
// PATH 0, grid (83,128): bx==0 -> local_agg -> d_out; bx 1..7 -> mode0 -> out0;
//                        bx 8..82 -> mode1 -> out1.
// PATH 2, grid (7,128):  mode2 (self=out0, neigh=out1, hop1) += d_out.
//
// Register discipline (r5-r7 lessons): unified-file budget at 4 waves/SIMD is
// 128; arch + GEMM1 acc (48 AGPR) + GEMM2 acc must stay under it, and the
// allocator does NOT overlap accumulator lifetimes across GEMMs. Hence GEMM2
// is the small A2[16x256] form (4 AGPR, 16 MFMA) with phase-4 computing
// neigh = sum_s alpha*nv into A2's upper half. No per-lane f32 array may
// live across an MFMA loop (spill -> 600+ MB scratch traffic).
// ---------------------------------------------------------------------------
template <int PATH>
__global__ __launch_bounds__(256, 4) void main_kernel(
    const int* __restrict__ inputs, const int* __restrict__ adj,
    const u16* __restrict__ emb_bf, const float* __restrict__ a_local,
    const int* __restrict__ n1, const int* __restrict__ n2p,
    const int* __restrict__ n1p,
    const float* __restrict__ nw0, const float* __restrict__ nw1,
    const u16* __restrict__ sw1, const float* __restrict__ w1,
    const float* __restrict__ w2, const u16* __restrict__ w3t,
    const u16* __restrict__ in0, const u16* __restrict__ in1,
    u16* __restrict__ o0, u16* __restrict__ o1, float* __restrict__ outf)
{
    __shared__ __align__(16) char smem[35072];
    const int b = blockIdx.y;
    const int t = threadIdx.x;
    const int bx = blockIdx.x;

    if (PATH == 0 && bx == 0) {
        // ------------------- local aggregation (conflict-free layout) -----
        u16*   ht    = (u16*)smem;              // [128][52] bf16 = 13312 B
        float* alpha = (float*)(smem + 13312);  // [50][51] f32  = 10200 B
        u16*   alb   = (u16*)(smem + 23520);    // [4][128] bf16 = 1024 B

        for (int idx = t; idx < S * D; idx += 256) {
            int i = idx >> 7, d = idx & 127;
            ht[d * 52 + i] = emb_bf[(size_t)inputs[b * S + i] * D + d];
        }
        for (int idx = t; idx < 512; idx += 256) alb[idx] = f2bf(a_local[idx]);
        __syncthreads();

        for (int p = t; p < S * S; p += 256) {
            int i = p / S, j = p % S;
            int a = adj[b * S * S + p];
            float v = -9e15f;
            if (a >= 1 && a <= 4) {
                const u16* ak = alb + (a - 1) * D;
                float dot = 0.f;
                #pragma unroll 4
                for (int d = 0; d < D; ++d)
                    dot += bf2f(ht[d * 52 + i]) * bf2f(ht[d * 52 + j]) * bf2f(ak[d]);
                v = leakyf(dot);
            }
            alpha[i * 51 + j] = v;
        }
        __syncthreads();

        if (t < S) {
            float m = -INFINITY;
            for (int j = 0; j < S; ++j) m = fmaxf(m, alpha[t * 51 + j]);
            float ssum = 0.f;
            for (int j = 0; j < S; ++j) { float e = __expf(alpha[t * 51 + j] - m); alpha[t * 51 + j] = e; ssum += e; }
            float inv = 1.f / ssum;
            for (int j = 0; j < S; ++j) alpha[t * 51 + j] *= inv;
        }
        __syncthreads();

        for (int idx = t; idx < S * D; idx += 256) {
            int i = idx >> 7, d = idx & 127;
            float acc = 0.f;
            #pragma unroll 5
            for (int j = 0; j < S; ++j) acc += alpha[i * 51 + j] * bf2f(ht[d * 52 + j]);
            outf[(size_t)b * S * D + idx] = acc;
        }
        return;
    }

    // ------------------- global aggregation -------------------
    int mode, lblk, L, Lm, hop;
    const u16 *nsrc, *ssrc;
    const int* ptab; const float* nwTab;
    u16* outb;
    if (PATH == 2)    { mode = 2; lblk = bx;     L = 50;  Lm = 600;  hop = 1; nsrc = in1;    ssrc = in0;    ptab = nullptr;                   nwTab = nw0; outb = nullptr; }
    else if (bx >= 8) { mode = 1; lblk = bx - 8; L = 600; Lm = 7200; hop = 0; nsrc = emb_bf; ssrc = emb_bf; ptab = n2p + (b * 75 + lblk) * 96; nwTab = nw1; outb = o1; }
    else              { mode = 0; lblk = bx - 1; L = 50;  Lm = 600;  hop = 0; nsrc = emb_bf; ssrc = emb_bf; ptab = n1p + (b * 7 + lblk) * 96;  nwTab = nw0; outb = o0; }
    const int l0 = lblk * 8;

    u16*   nvL     = (u16*)smem;              // 1536 slots * 16B = 24576 (XOR-swizzled)
    u16*   A2      = (u16*)(smem + 24576);    // 512 slots * 16B = 8192 ([self|neigh], 16x256)
    float* score_w = (float*)(smem + 32768);  // [96][4] = 1536
    float* nwgtL   = (float*)(smem + 34304);  // 96 floats
    float* alphL   = (float*)(smem + 34688);  // 96 floats (l-major: [l][s])

    const u16*   sw1b   = sw1 + (size_t)(hop * 128 + b) * 16384;
    const float* w1last = w1 + hop * 129 * 128 + 128 * 128;
    const float* w2h    = w2 + hop * 128;
    const u16*   w3th   = w3t + hop * 32768;

    const int lane = t & 63, wv = t >> 6, cn = lane & 15, cg = lane >> 4;
    const int nc0 = (2 * wv) * 16 + cn, nc1 = (2 * wv + 1) * 16 + cn;
    const int cS = t & 15;       // physical slot position within 16-group
    const int chunk = t >> 4;    // 16B k-chunk 0..15 of a 256B row (= kk*4+cg2)

    // ---- stage neighbor rows: linear slot write, row choice XOR-permuted ----
    {
        int kkS = t >> 6, cgS = (t >> 4) & 3;
        int cn2 = cS ^ swz(cgS, kkS);          // logical fragment row position
        #pragma unroll
        for (int i = 0; i < 6; ++i) {
            int off;
            if (PATH == 2) {
                int gm = l0 * 12 + (cn2 >> 2) * 24 + i * 4 + (cn2 & 3);
                if (gm > 599) gm = 599;
                off = (b * 600 + gm) << 8;
            } else {
                off = ptab[i * 16 + cn2];      // same table, permuted index
            }
            uint4 v = *reinterpret_cast<const uint4*>((const char*)nsrc + (unsigned)off + chunk * 16);
            *reinterpret_cast<uint4*>(nvL + (i * 256 + t) * 8) = v;
        }
    }
    // ---- stage self rows into A2 lower half (k 0..127); rows 8..15 = 0 ----
    {
        uint4 v = make_uint4(0, 0, 0, 0);
        if (cS < 8) {
            int lg = l0 + cS; if (lg >= L) lg = 0;
            int srow;
            if (PATH == 2)      srow = b * 50 + lg;
            else if (mode == 1) srow = n1[b * 600 + lg];
            else                srow = inputs[b * S + lg];
            v = *reinterpret_cast<const uint4*>(ssrc + (size_t)srow * 128 + chunk * 8);
        }
        *reinterpret_cast<uint4*>(A2 + t * 8) = v;     // slot = (t>>6)*64 + lane
    }
    // zero A2 upper half's pad rows 8..15 (phase 4 writes only rows 0..7)
    if (t < 128) {
        int slot = (4 + (t >> 5)) * 64 + ((t >> 3) & 3) * 16 + 8 + (t & 7);
        *reinterpret_cast<uint4*>(A2 + slot * 8) = make_uint4(0, 0, 0, 0);
    }
    if (t < 96) {
        int gm = l0 * 12 + t;
        nwgtL[t] = (gm < Lm) ? nwTab[b * Lm + gm] : 0.f;
    }
    __syncthreads();

    // ---- GEMM1: z[96,128] = nv @ sessW1 ----
    f32x4 acc[6][2];
    #pragma unroll
    for (int mt = 0; mt < 6; ++mt) {
        acc[mt][0] = (f32x4){0.f, 0.f, 0.f, 0.f};
        acc[mt][1] = (f32x4){0.f, 0.f, 0.f, 0.f};
    }
    #pragma unroll
    for (int kk = 0; kk < 4; ++kk) {
        int kb = kk * 32 + cg * 8;
        int lslot = cg * 16 + (cn ^ swz(cg, kk));      // swizzled lane slot
        short8v b0 = *reinterpret_cast<const short8v*>(sw1b + nc0 * 128 + kb);
        short8v b1 = *reinterpret_cast<const short8v*>(sw1b + nc1 * 128 + kb);
        #pragma unroll
        for (int mt = 0; mt < 6; ++mt) {
            short8v a = *reinterpret_cast<const short8v*>(nvL + ((mt * 4 + kk) * 64 + lslot) * 8);
            acc[mt][0] = __builtin_amdgcn_mfma_f32_16x16x32_bf16(a, b0, acc[mt][0], 0, 0, 0);
            acc[mt][1] = __builtin_amdgcn_mfma_f32_16x16x32_bf16(a, b1, acc[mt][1], 0, 0, 0);
        }
    }
    // ---- score epilogue: K=129 rank-1 + leaky + @W2, reduce over 16 lanes ----
    {
        float w2v0 = w2h[nc0], w2v1 = w2h[nc1];
        float w1l0 = w1last[nc0], w1l1 = w1last[nc1];
        #pragma unroll
        for (int mt = 0; mt < 6; ++mt) {
            #pragma unroll
            for (int r = 0; r < 4; ++r) {
                int m = cg * 24 + mt * 4 + r;
                float nw = nwgtL[m];
                float v = leakyf(acc[mt][0][r] + nw * w1l0) * w2v0 +
                          leakyf(acc[mt][1][r] + nw * w1l1) * w2v1;
                v += __shfl_xor(v, 1); v += __shfl_xor(v, 2);
                v += __shfl_xor(v, 4); v += __shfl_xor(v, 8);
                if (cn == 0) score_w[m * 4 + wv] = v;
            }
        }
    }
    __syncthreads();

    // ---- per-lane redundant softmax for l=2cg,2cg+1 -> alphL (l-major) ----
    {
        float alph[24];
        const f32x4* sw4 = reinterpret_cast<const f32x4*>(score_w);
        float mx0 = -1e30f, mx1 = -1e30f;
        #pragma unroll
        for (int q = 0; q < 24; ++q) {
            f32x4 s4 = sw4[cg * 24 + q];
            float s = (s4[0] + s4[1]) + (s4[2] + s4[3]);
            alph[q] = s;
            if (q < 12) mx0 = fmaxf(mx0, s); else mx1 = fmaxf(mx1, s);
        }
        float sm0 = 0.f, sm1 = 0.f;
        #pragma unroll
        for (int q = 0; q < 12; ++q) { alph[q] = __expf(alph[q] - mx0); sm0 += alph[q]; }
        #pragma unroll
        for (int q = 12; q < 24; ++q) { alph[q] = __expf(alph[q] - mx1); sm1 += alph[q]; }
        float i0 = 1.f / sm0, i1 = 1.f / sm1;
        // every wave writes all 96 slots (identical values); phase-4 readers
        // are same-wave, so ds ordering suffices (no barrier needed)
        if (cn == 0) {
            #pragma unroll
            for (int q = 0; q < 12; ++q)  alphL[(cg * 2) * 12 + q] = alph[q] * i0;
            #pragma unroll
            for (int q = 12; q < 24; ++q) alphL[(cg * 2 + 1) * 12 + (q - 12)] = alph[q] * i1;
        }
    }

    // ---- phase 4: neigh[l][d] = sum_s alpha*nv -> A2 upper (k 128..255) ----
    #pragma unroll 1
    for (int i = 0; i < 4; ++i) {
        int idx = i * 256 + t;
        int l = idx >> 7, d = idx & 127;
        int kkd = d >> 5, cgd = (d >> 3) & 3, el = d & 7;
        int cnb = (l >> 1) * 4;         // cn2 base for this l
        int mtb = (l & 1) * 3;          // mt base for this l
        int fd = swz(cgd, kkd);
        float a = 0.f;
        #pragma unroll
        for (int s = 0; s < 12; ++s) {
            int slot = ((mtb + (s >> 2)) * 4 + kkd) * 64 + cgd * 16 + ((cnb + (s & 3)) ^ fd);
            a += alphL[l * 12 + s] * bf2f(nvL[slot * 8 + el]);
        }
        int slot2 = (4 + kkd) * 64 + cgd * 16 + l;
        A2[slot2 * 8 + el] = f2bf(a);
    }
    __syncthreads();

    // ---- GEMM2: out[16,128] = A2[16,256] @ W3T (4 AGPR, 16 MFMA/wave) ----
    #pragma unroll
    for (int j = 0; j < 2; ++j) {
        int nc = (2 * wv + j) * 16 + cn;
        f32x4 acc2 = (f32x4){0.f, 0.f, 0.f, 0.f};
        #pragma unroll
        for (int kk2 = 0; kk2 < 8; ++kk2) {
            short8v a2 = *reinterpret_cast<const short8v*>(A2 + (kk2 * 64 + lane) * 8);
            short8v bb = *reinterpret_cast<const short8v*>(w3th + nc * 256 + kk2 * 32 + cg * 8);
            acc2 = __builtin_amdgcn_mfma_f32_16x16x32_bf16(a2, bb, acc2, 0, 0, 0);
        }
        if (cg < 2) {                    // C rows 0..7 = l; rows 8..15 are pad
            #pragma unroll
            for (int r = 0; r < 4; ++r) {
                int l = cg * 4 + r;
                int lg = l0 + l;
                float v = fmaxf(acc2[r], 0.f);
                if (lg < L) {
                    if (PATH == 2) { float* p = outf + ((size_t)b * 50 + lg) * 128 + nc; *p += v; }
                    else           outb[((size_t)b * L + lg) * 128 + nc] = f2bf(v);
                }
            }
        }
    }
}

// ---------------------------------------------------------------------------
extern "C" void kernel_launch(void* const* d_in, const int* in_sizes, int n_in,
                              void* d_out, int out_size, void* d_ws, size_t ws_size,
                              hipStream_t stream)
{
    const int*   inputs     = (const int*)d_in[0];
    const int*   adj        = (const int*)d_in[1];
    const int*   mask_item  = (const int*)d_in[2];
    const int*   item       = (const int*)d_in[3];
    const int*   adj_all    = (const int*)d_in[4];
    const float* num_weight = (const float*)d_in[5];
    const float* embedding  = (const float*)d_in[6];
    const float* a_local    = (const float*)d_in[7];
    const float* agg_w1     = (const float*)d_in[8];
    const float* agg_w2     = (const float*)d_in[9];
    const float* agg_w3     = (const float*)d_in[10];
    float* out = (float*)d_out;

    // workspace layout (16B aligned)
    char* w = (char*)d_ws;
    float* ws_session = (float*)(w);               //     65,536 B
    int*   ws_n1      = (int*)(w + 65536);         //    307,200 B
    float* ws_nw0     = (float*)(w + 372736);      //    307,200 B
    float* ws_nw1     = (float*)(w + 679936);      //  3,686,400 B
    int*   ws_n2p     = (int*)(w + 4366336);       //  3,686,400 B
    int*   ws_n1p     = (int*)(w + 8052736);       //    344,064 B
    u16*   ws_emb     = (u16*)(w + 8396800);       // 10,240,000 B
    u16*   ws_sw1     = (u16*)(w + 18636800);      //  8,388,608 B
    u16*   ws_w3t     = (u16*)(w + 27025408);      //    131,072 B
    u16*   ws_out0    = (u16*)(w + 27156480);      //  1,638,400 B
    u16*   ws_out1    = (u16*)(w + 28794880);      // 19,660,800 B (end ~46.2 MB)

    setup1_kernel<<<dim3(BATCH + 300), 256, 0, stream>>>(
        item, mask_item, inputs, adj_all, num_weight, embedding,
        ws_session, ws_n1, ws_nw0);
    prep2_kernel<<<dim3(6724), 256, 0, stream>>>(
        embedding, agg_w1, agg_w3, ws_session, adj_all, num_weight, ws_n1,
        ws_emb, ws_sw1, ws_w3t, ws_n2p, ws_n1p, ws_nw1);

    // fused: local (bx=0) + mode0 (bx 1..7) + mode1 (bx 8..82) per batch
    main_kernel<0><<<dim3(83, BATCH), 256, 0, stream>>>(
        inputs, adj, ws_emb, a_local, ws_n1, ws_n2p, ws_n1p, ws_nw0, ws_nw1,
        ws_sw1, agg_w1, agg_w2, ws_w3t,
        nullptr, nullptr, ws_out0, ws_out1, out);

    // mode2: hop-1 weights, self=out0, neigh=out1, += h_local in d_out
    main_kernel<2><<<dim3(7, BATCH), 256, 0, stream>>>(
        inputs, adj, ws_emb, a_local, ws_n1, ws_n2p, ws_n1p, ws_nw0, ws_nw1,
        ws_sw1, agg_w1, agg_w2, ws_w3t,
        ws_out0, ws_out1, nullptr, nullptr, out);
}